// Round 7
// baseline (150.280 us; speedup 1.0000x reference)
//
#include <hip/hip_runtime.h>
#include <stdint.h>

// GCN: h = relu( D^-1/2 (A+I) D^-1/2 (x@W1) + b1 ); z = h@W2 + b2
// out = [h (N*3) | z (N*7)] float32.
//
// Round-7:
//  - xw1 role was DS-pipe bound: 15 shuffles/node (1.5M wave-DS-ops ~ 15-30us).
//    New F=16/M=4 scheme: wave= 4 nodes, lane=(node l>>4, featblk l&15),
//    16 features/lane in registers, width-16 reduce = 3 DS-ops/node (5x less).
//  - bin role TLP x5.4: nbin 190 -> ~1020 fixed-strip blocks (STRIDE 16).
//    Per-strip lambda=8, P(>16)~0.003 -> ~1.3K exact spills (OVFCAP 8192).
//  - consumers SPLIT up to 16; strip masks via pcnt; cascade geometries by ws.
// Norm factored: agg[d] = dinv[d]*( sum_{s->d} h[s]dinv[s] + h[d]dinv[d] ).

#define BSHIFT 8
#define BNODES 256
#define OVFCAP 8192
#define PSTRIDE 1024  // pcnt row stride, >= nbin for all geometries

// block-wide int64-vs-int32 ballot: int64 LE => odd 32-bit words of first 256
// entries are all zero (ids < 2^17). Call from ALL threads before divergence.
__device__ __forceinline__ bool ei_is64(const unsigned* __restrict__ ei) {
    const int t = threadIdx.x;
    const int nz = (t < 256) && (ei[2 * t + 1] != 0u);
    return __syncthreads_or(nz) == 0;
}

// ---------- fused: [one-pass strip-bin role | x@W1 role] ----------
template <int SSH>  // strip size = 1<<SSH
__global__ __launch_bounds__(512) void k_pre(const float* __restrict__ x,
                                             const float* __restrict__ W1,
                                             float* __restrict__ g4,
                                             const unsigned* __restrict__ ei,
                                             unsigned* __restrict__ records,
                                             unsigned* __restrict__ pcnt,
                                             unsigned* __restrict__ ovf_cnt,
                                             unsigned* __restrict__ ovf,
                                             int E, int B, int CAP, int CH,
                                             int nbin, int N) {
    const bool is64 = ei_is64(ei);
    if ((int)blockIdx.x < nbin) {
        // ---- bin role: scatter 4B records into this block's fixed strips ----
        __shared__ unsigned cursor[512];
        for (int i = threadIdx.x; i < B; i += 512) cursor[i] = 0u;
        __syncthreads();
        const int e0 = blockIdx.x * CH;
        const int e1 = min(E, e0 + CH);
        const unsigned sbase = blockIdx.x << SSH;

        auto emit = [&](unsigned s, unsigned d) {
            const unsigned bb  = d >> BSHIFT;
            const unsigned idx = atomicAdd(&cursor[bb], 1u);
            if (idx < (1u << SSH)) {
                records[(size_t)bb * CAP + sbase + idx] = (s << BSHIFT) | (d & (BNODES - 1));
            } else {
                const unsigned o = atomicAdd(ovf_cnt, 1u);
                if (o < OVFCAP) { ovf[2 * o] = s; ovf[2 * o + 1] = d; }
            }
        };

        const int nq = (e1 - e0) >> 2;
        if (is64) {
            const unsigned long long* e64 = (const unsigned long long*)ei;
            const ulonglong2* sp = (const ulonglong2*)(e64 + e0);
            const ulonglong2* dp = (const ulonglong2*)(e64 + (size_t)E + e0);
            for (int q = threadIdx.x; q < nq; q += 512) {
                const ulonglong2 sa = sp[2 * q], sb = sp[2 * q + 1];
                const ulonglong2 da = dp[2 * q], db = dp[2 * q + 1];
                emit((unsigned)sa.x, (unsigned)da.x);
                emit((unsigned)sa.y, (unsigned)da.y);
                emit((unsigned)sb.x, (unsigned)db.x);
                emit((unsigned)sb.y, (unsigned)db.y);
            }
            for (int e = e0 + 4 * nq + threadIdx.x; e < e1; e += 512)
                emit((unsigned)e64[e], (unsigned)e64[(size_t)E + e]);
        } else {
            const uint4* sp = (const uint4*)(ei + e0);
            const uint4* dp = (const uint4*)(ei + (size_t)E + e0);
            for (int q = threadIdx.x; q < nq; q += 512) {
                const uint4 s4 = sp[q], d4 = dp[q];
                emit(s4.x, d4.x);
                emit(s4.y, d4.y);
                emit(s4.z, d4.z);
                emit(s4.w, d4.w);
            }
            for (int e = e0 + 4 * nq + threadIdx.x; e < e1; e += 512)
                emit(ei[e], ei[(size_t)E + e]);
        }
        __syncthreads();
        for (int i = threadIdx.x; i < B; i += 512)
            pcnt[(size_t)i * PSTRIDE + blockIdx.x] = min(cursor[i], 1u << SSH);
    } else {
        // ---- x@W1 role: wave = 4 nodes; lane m=l>>4 node-sub, fg=l&15 ----
        const int bx      = blockIdx.x - nbin;
        const int gtid    = bx * 512 + threadIdx.x;
        const int nthread = ((int)gridDim.x - nbin) * 512;
        const int lane    = threadIdx.x & 63;
        const int fg      = lane & 15;
        const int m       = lane >> 4;
        float w[4][4][3];
#pragma unroll
        for (int p = 0; p < 4; ++p)
#pragma unroll
            for (int j = 0; j < 4; ++j)
#pragma unroll
                for (int c = 0; c < 3; ++c)
                    w[p][j][c] = W1[(fg * 4 + p * 64 + j) * 3 + c];
        const int wave   = gtid >> 6;
        const int nwaves = nthread >> 6;
        for (int nb4 = wave * 4; nb4 < N; nb4 += nwaves * 4) {
            const int node = nb4 + m;
            float s0 = 0.f, s1 = 0.f, s2 = 0.f;
            if (node < N) {
                const float* row = x + (size_t)node * 256 + fg * 4;
#pragma unroll
                for (int p = 0; p < 4; ++p) {
                    const float4 v = *reinterpret_cast<const float4*>(row + p * 64);
                    s0 += v.x * w[p][0][0] + v.y * w[p][1][0] + v.z * w[p][2][0] + v.w * w[p][3][0];
                    s1 += v.x * w[p][0][1] + v.y * w[p][1][1] + v.z * w[p][2][1] + v.w * w[p][3][1];
                    s2 += v.x * w[p][0][2] + v.y * w[p][1][2] + v.z * w[p][2][2] + v.w * w[p][3][2];
                }
            }
#pragma unroll
            for (int off = 8; off >= 1; off >>= 1) {  // width-16 reduce, 4 nodes at once
                s0 += __shfl_xor(s0, off, 64);
                s1 += __shfl_xor(s1, off, 64);
                s2 += __shfl_xor(s2, off, 64);
            }
            if (fg == 0 && node < N)
                reinterpret_cast<float4*>(g4)[node] = make_float4(s0, s1, s2, 0.f);
        }
    }
}

// ---------- per-(bucket,slice) degree histogram -> coalesced u32 partials ----
template <int SSH>
__global__ __launch_bounds__(256) void k_cnt2(const unsigned* __restrict__ records,
                                              const unsigned* __restrict__ pcnt,
                                              const unsigned* __restrict__ ovf_cnt,
                                              const unsigned* __restrict__ ovf,
                                              unsigned* __restrict__ pcount,
                                              int B, int CAP, int SPLIT, int nbin) {
    __shared__ unsigned cnt[BNODES];
    __shared__ unsigned scnt[PSTRIDE];
    const int b  = blockIdx.x / SPLIT;
    const int sl = blockIdx.x - b * SPLIT;
    cnt[threadIdx.x] = 0u;
    for (int i = threadIdx.x; i < nbin; i += 256) scnt[i] = pcnt[(size_t)b * PSTRIDE + i];
    __syncthreads();
    const int per = CAP / SPLIT;
    const int lo = sl * per, hi = lo + per;
    const unsigned* rec = records + (size_t)b * CAP;
    for (int k = lo + threadIdx.x; k < hi; k += 256) {
        if ((unsigned)(k & ((1 << SSH) - 1)) < scnt[k >> SSH])
            atomicAdd(&cnt[rec[k] & (BNODES - 1)], 1u);
    }
    if (sl == 0) {
        unsigned no = *ovf_cnt; if (no > OVFCAP) no = OVFCAP;
        for (unsigned i = threadIdx.x; i < no; i += 256) {
            const unsigned d = ovf[2 * i + 1];
            if ((int)(d >> BSHIFT) == b) atomicAdd(&cnt[d & (BNODES - 1)], 1u);
        }
    }
    __syncthreads();
    pcount[((size_t)blockIdx.x << BSHIFT) + threadIdx.x] = cnt[threadIdx.x];
}

// ---------- reduce count partials -> dinv; g4 = {h*dinv, dinv} ----------
__global__ __launch_bounds__(256) void k_dinv2(const unsigned* __restrict__ pcount,
                                               float* __restrict__ g4, int N, int SPLIT) {
    const int i = blockIdx.x * 256 + threadIdx.x;
    if (i >= N) return;
    const int b = i >> BSHIFT, t = i & (BNODES - 1);
    unsigned deg = 1u;  // self-loop
    for (int s = 0; s < SPLIT; ++s)
        deg += pcount[(((size_t)b * SPLIT + s) << BSHIFT) + t];
    const float r = rsqrtf((float)deg);
    const float4 h = reinterpret_cast<const float4*>(g4)[i];
    reinterpret_cast<float4*>(g4)[i] = make_float4(h.x * r, h.y * r, h.z * r, r);
}

// ---------- per-(bucket,slice) message accumulate -> coalesced f32 partials ----
template <int SSH>
__global__ __launch_bounds__(256) void k_msg2(const unsigned* __restrict__ records,
                                              const unsigned* __restrict__ pcnt,
                                              const unsigned* __restrict__ ovf_cnt,
                                              const unsigned* __restrict__ ovf,
                                              const float* __restrict__ g4,
                                              float* __restrict__ psum,
                                              int B, int CAP, int SPLIT, int nbin) {
    __shared__ float acc[BNODES * 3];
    __shared__ unsigned scnt[PSTRIDE];
    const int b  = blockIdx.x / SPLIT;
    const int sl = blockIdx.x - b * SPLIT;
    for (int i = threadIdx.x; i < BNODES * 3; i += 256) acc[i] = 0.f;
    for (int i = threadIdx.x; i < nbin; i += 256) scnt[i] = pcnt[(size_t)b * PSTRIDE + i];
    __syncthreads();
    const int per = CAP / SPLIT;
    const int lo = sl * per, hi = lo + per;
    const unsigned* rec = records + (size_t)b * CAP;
    const float4* g4v = reinterpret_cast<const float4*>(g4);
    for (int k = lo + threadIdx.x; k < hi; k += 256) {
        if ((unsigned)(k & ((1 << SSH) - 1)) < scnt[k >> SSH]) {
            const unsigned r = rec[k];
            const float4 g = g4v[r >> BSHIFT];
            const unsigned l = (r & (BNODES - 1)) * 3;
            atomicAdd(&acc[l + 0], g.x);
            atomicAdd(&acc[l + 1], g.y);
            atomicAdd(&acc[l + 2], g.z);
        }
    }
    if (sl == 0) {
        unsigned no = *ovf_cnt; if (no > OVFCAP) no = OVFCAP;
        for (unsigned i = threadIdx.x; i < no; i += 256) {
            const unsigned d = ovf[2 * i + 1];
            if ((int)(d >> BSHIFT) == b) {
                const float4 g = g4v[ovf[2 * i]];
                const unsigned l = (d & (BNODES - 1)) * 3;
                atomicAdd(&acc[l + 0], g.x);
                atomicAdd(&acc[l + 1], g.y);
                atomicAdd(&acc[l + 2], g.z);
            }
        }
    }
    __syncthreads();
    const size_t base = ((size_t)blockIdx.x * 3) << BSHIFT;  // [slice][c][256]
    psum[base +   0 + threadIdx.x] = acc[threadIdx.x * 3 + 0];
    psum[base + 256 + threadIdx.x] = acc[threadIdx.x * 3 + 1];
    psum[base + 512 + threadIdx.x] = acc[threadIdx.x * 3 + 2];
}

// ---------- reduce msg partials + fused epilogue ----------
__global__ __launch_bounds__(256) void k_fin(const float* __restrict__ psum,
                                             const float* __restrict__ g4,
                                             const float* __restrict__ b1,
                                             const float* __restrict__ W2,
                                             const float* __restrict__ b2,
                                             float* __restrict__ out, int N, int SPLIT) {
    const int i = blockIdx.x * 256 + threadIdx.x;
    if (i >= N) return;
    const int b = i >> BSHIFT, t = i & (BNODES - 1);
    float a0 = 0.f, a1 = 0.f, a2 = 0.f;
    for (int s = 0; s < SPLIT; ++s) {
        const size_t base = (((size_t)b * SPLIT + s) * 3) << BSHIFT;
        a0 += psum[base + t];
        a1 += psum[base + 256 + t];
        a2 += psum[base + 512 + t];
    }
    const float4 g = reinterpret_cast<const float4*>(g4)[i];
    const float  r = g.w;
    const float h0 = fmaxf(r * (a0 + g.x) + b1[0], 0.f);
    const float h1 = fmaxf(r * (a1 + g.y) + b1[1], 0.f);
    const float h2 = fmaxf(r * (a2 + g.z) + b1[2], 0.f);
    out[3 * (size_t)i + 0] = h0;
    out[3 * (size_t)i + 1] = h1;
    out[3 * (size_t)i + 2] = h2;
    float* z = out + (size_t)3 * N;
#pragma unroll
    for (int c = 0; c < 7; ++c)
        z[7 * (size_t)i + c] = h0 * W2[c] + h1 * W2[7 + c] + h2 * W2[14 + c] + b2[c];
}

// ================= fallback (atomic path; only if ws too small) =============
__global__ __launch_bounds__(256) void k_xw1_fb(const float* __restrict__ x,
                                                const float* __restrict__ W1,
                                                float* __restrict__ g4,
                                                unsigned* __restrict__ zptr,
                                                int nzero, int N) {
    const int gtid = blockIdx.x * 256 + threadIdx.x;
    const int nthread = gridDim.x * 256;
    for (int i = gtid; i < nzero; i += nthread) zptr[i] = 0u;
    const int lane = threadIdx.x & 63;
    float w[4][3];
#pragma unroll
    for (int k = 0; k < 4; ++k)
#pragma unroll
        for (int c = 0; c < 3; ++c) w[k][c] = W1[(lane * 4 + k) * 3 + c];
    const int wave = gtid >> 6, nwaves = nthread >> 6;
    for (int node = wave; node < N; node += nwaves) {
        const float4 v = *reinterpret_cast<const float4*>(x + (size_t)node * 256 + lane * 4);
        float s0 = v.x * w[0][0] + v.y * w[1][0] + v.z * w[2][0] + v.w * w[3][0];
        float s1 = v.x * w[0][1] + v.y * w[1][1] + v.z * w[2][1] + v.w * w[3][1];
        float s2 = v.x * w[0][2] + v.y * w[1][2] + v.z * w[2][2] + v.w * w[3][2];
#pragma unroll
        for (int off = 32; off > 0; off >>= 1) {
            s0 += __shfl_xor(s0, off, 64);
            s1 += __shfl_xor(s1, off, 64);
            s2 += __shfl_xor(s2, off, 64);
        }
        if (lane == 0)
            reinterpret_cast<float4*>(g4)[node] = make_float4(s0, s1, s2, 0.f);
    }
}
__global__ __launch_bounds__(256) void k_deg_fb(const unsigned* __restrict__ ei,
                                                float* __restrict__ deg, int E) {
    const bool is64 = ei_is64(ei);
    const int e = blockIdx.x * 256 + threadIdx.x;
    if (e >= E) return;
    const unsigned d = is64 ? (unsigned)((const unsigned long long*)ei)[(size_t)E + e]
                            : ei[(size_t)E + e];
    atomicAdd(&deg[d], 1.0f);
}
__global__ __launch_bounds__(256) void k_dinv_fb(const float* __restrict__ deg,
                                                 float* __restrict__ g4, int N) {
    const int i = blockIdx.x * 256 + threadIdx.x;
    if (i >= N) return;
    const float r = rsqrtf(1.0f + deg[i]);
    const float4 h = reinterpret_cast<const float4*>(g4)[i];
    reinterpret_cast<float4*>(g4)[i] = make_float4(h.x * r, h.y * r, h.z * r, r);
}
__global__ __launch_bounds__(256) void k_edge_fb(const unsigned* __restrict__ ei,
                                                 const float* __restrict__ g4,
                                                 float* __restrict__ u4, int E) {
    const bool is64 = ei_is64(ei);
    const int e = blockIdx.x * 256 + threadIdx.x;
    if (e >= E) return;
    unsigned s, d;
    if (is64) {
        const unsigned long long* q = (const unsigned long long*)ei;
        s = (unsigned)q[e]; d = (unsigned)q[(size_t)E + e];
    } else {
        s = ei[e]; d = ei[(size_t)E + e];
    }
    const float4 g = reinterpret_cast<const float4*>(g4)[s];
    atomicAdd(&u4[4 * (size_t)d + 0], g.x);
    atomicAdd(&u4[4 * (size_t)d + 1], g.y);
    atomicAdd(&u4[4 * (size_t)d + 2], g.z);
}
__global__ __launch_bounds__(256) void k_final_fb(const float* __restrict__ u4,
                                                  const float* __restrict__ g4,
                                                  const float* __restrict__ b1,
                                                  const float* __restrict__ W2,
                                                  const float* __restrict__ b2,
                                                  float* __restrict__ out, int N) {
    const int i = blockIdx.x * 256 + threadIdx.x;
    if (i >= N) return;
    const float4 g = reinterpret_cast<const float4*>(g4)[i];
    const float4 u = reinterpret_cast<const float4*>(u4)[i];
    const float  r = g.w;
    const float h0 = fmaxf(r * (u.x + g.x) + b1[0], 0.f);
    const float h1 = fmaxf(r * (u.y + g.y) + b1[1], 0.f);
    const float h2 = fmaxf(r * (u.z + g.z) + b1[2], 0.f);
    out[3 * (size_t)i + 0] = h0;
    out[3 * (size_t)i + 1] = h1;
    out[3 * (size_t)i + 2] = h2;
    float* z = out + (size_t)3 * N;
#pragma unroll
    for (int c = 0; c < 7; ++c)
        z[7 * (size_t)i + c] = h0 * W2[c] + h1 * W2[7 + c] + h2 * W2[14 + c] + b2[c];
}

extern "C" void kernel_launch(void* const* d_in, const int* in_sizes, int n_in,
                              void* d_out, int out_size, void* d_ws, size_t ws_size,
                              hipStream_t stream) {
    const float*    x   = (const float*)d_in[0];
    const unsigned* ei  = (const unsigned*)d_in[1];
    const float*    W1  = (const float*)d_in[2];
    const float*    b1  = (const float*)d_in[3];
    const float*    W2  = (const float*)d_in[4];
    const float*    b2  = (const float*)d_in[5];
    float*          out = (float*)d_out;

    const int N = in_sizes[0] / 256;          // 100000
    const int E = in_sizes[1] / 2;            // 3200000
    const int B = (N + BNODES - 1) >> BSHIFT; // 391

    // geometry A: ~1020 bin blocks, STRIDE 16 (lambda~8/strip)
    const int CH_A   = ((E + 1019) / 1020 + 3) & ~3;
    const int nbin_A = (E + CH_A - 1) / CH_A;       // <= 1020
    const int CAP_A  = nbin_A << 4;
    // geometry B: ~190 bin blocks, STRIDE 64 (round-6 proven)
    const int CH_B   = ((E + 189) / 190 + 3) & ~3;
    const int nbin_B = (E + CH_B - 1) / CH_B;       // <= 190
    const int CAP_B  = nbin_B << 6;

    // ---- workspace layout ----
    char*     ws      = (char*)d_ws;
    unsigned* ovf_cnt = (unsigned*)ws;                      // 1 word
    size_t off = 256;
    float*    g4  = (float*)(ws + off);                     // 4N {h*dinv, dinv}
    off = (off + 16ull * N + 255) & ~(size_t)255;
    unsigned* ovf = (unsigned*)(ws + off);                  // 2*OVFCAP
    off = (off + 8ull * OVFCAP + 255) & ~(size_t)255;
    unsigned* pcnt = (unsigned*)(ws + off);                 // B*PSTRIDE strip counts
    off = (off + 4ull * B * PSTRIDE + 255) & ~(size_t)255;
    const size_t puoff = off;                               // pcount/psum overlay

    // pick (geometry, SPLIT) that fits ws
    struct Cfg { int ssh, nbin, cap, ch, split; size_t rec_off; };
    Cfg cfg{0, 0, 0, 0, 0, 0};
    const int geo_ssh[2]  = {4, 6};
    const int geo_nbin[2] = {nbin_A, nbin_B};
    const int geo_cap[2]  = {CAP_A, CAP_B};
    const int geo_ch[2]   = {CH_A, CH_B};
    const int sps[3]      = {16, 8, 4};
    for (int gi = 0; gi < 2 && !cfg.split; ++gi) {
        for (int si = 0; si < 3 && !cfg.split; ++si) {
            const int sp = sps[si];
            const size_t ro = (puoff + 4ull * B * sp * 768 + 255) & ~(size_t)255;
            if (ws_size >= ro + 4ull * B * geo_cap[gi] + 4096) {
                cfg.ssh = geo_ssh[gi]; cfg.nbin = geo_nbin[gi]; cfg.cap = geo_cap[gi];
                cfg.ch = geo_ch[gi]; cfg.split = sp; cfg.rec_off = ro;
            }
        }
    }

    if (cfg.split) {
        unsigned* pcount  = (unsigned*)(ws + puoff);
        float*    psum    = (float*)(ws + puoff);           // overlay (cnt before msg)
        unsigned* records = (unsigned*)(ws + cfg.rec_off);
        hipMemsetAsync(ovf_cnt, 0, 4, stream);
        const int NBX = 1024;
        if (cfg.ssh == 4) {
            k_pre<4><<<cfg.nbin + NBX, 512, 0, stream>>>(x, W1, g4, ei, records, pcnt,
                                                         ovf_cnt, ovf, E, B, cfg.cap,
                                                         cfg.ch, cfg.nbin, N);
            k_cnt2<4><<<B * cfg.split, 256, 0, stream>>>(records, pcnt, ovf_cnt, ovf,
                                                         pcount, B, cfg.cap, cfg.split,
                                                         cfg.nbin);
        } else {
            k_pre<6><<<cfg.nbin + NBX, 512, 0, stream>>>(x, W1, g4, ei, records, pcnt,
                                                         ovf_cnt, ovf, E, B, cfg.cap,
                                                         cfg.ch, cfg.nbin, N);
            k_cnt2<6><<<B * cfg.split, 256, 0, stream>>>(records, pcnt, ovf_cnt, ovf,
                                                         pcount, B, cfg.cap, cfg.split,
                                                         cfg.nbin);
        }
        k_dinv2<<<(N + 255) / 256, 256, 0, stream>>>(pcount, g4, N, cfg.split);
        if (cfg.ssh == 4)
            k_msg2<4><<<B * cfg.split, 256, 0, stream>>>(records, pcnt, ovf_cnt, ovf, g4,
                                                         psum, B, cfg.cap, cfg.split,
                                                         cfg.nbin);
        else
            k_msg2<6><<<B * cfg.split, 256, 0, stream>>>(records, pcnt, ovf_cnt, ovf, g4,
                                                         psum, B, cfg.cap, cfg.split,
                                                         cfg.nbin);
        k_fin<<<(N + 255) / 256, 256, 0, stream>>>(psum, g4, b1, W2, b2, out, N, cfg.split);
    } else {
        // fallback: deg (N) + u4 (4N) after overlay base, zeroed in k_xw1_fb
        float* deg = (float*)(ws + puoff);
        float* u4  = deg + N;
        k_xw1_fb<<<4096, 256, 0, stream>>>(x, W1, g4, (unsigned*)deg, 5 * N, N);
        k_deg_fb<<<(E + 255) / 256, 256, 0, stream>>>(ei, deg, E);
        k_dinv_fb<<<(N + 255) / 256, 256, 0, stream>>>(deg, g4, N);
        k_edge_fb<<<(E + 255) / 256, 256, 0, stream>>>(ei, g4, u4, E);
        k_final_fb<<<(N + 255) / 256, 256, 0, stream>>>(u4, g4, b1, W2, b2, out, N);
    }
}